// Round 1
// baseline (331.395 us; speedup 1.0000x reference)
//
#include <hip/hip_runtime.h>

#define NCLS 19
#define HW   (512*1024)
#define NB   8
#define CHUNK 4096
#define EPSM  1e-6f
#define EPSPD 1e-6f

// ws layout (floats): sums[n][t][c][k]  (NB*2*19*19)  then counts[n][k] (NB*19)
#define SUMS_ELEMS (NB*2*NCLS*NCLS)
#define CNT_ELEMS  (NB*NCLS)

__global__ __launch_bounds__(256) void icl_sums(
    const float* __restrict__ S, const float* __restrict__ T,
    const int* __restrict__ gt, float* __restrict__ sums,
    float* __restrict__ counts)
{
    __shared__ int lab[CHUNK];
    __shared__ float hist[NCLS];

    const int n   = blockIdx.y;
    const int tid = threadIdx.x;
    const long pixbase = (long)blockIdx.x * CHUNK;

    if (tid < NCLS) hist[tid] = 0.f;
    __syncthreads();

    // stage labels (int4 vectorized) + per-block class histogram
    const int4* gp = (const int4*)(gt + (long)n * HW + pixbase);
    for (int i = tid; i < CHUNK / 4; i += 256) {
        int4 v = gp[i];
        ((int4*)lab)[i] = v;
        atomicAdd(&hist[v.x], 1.f);
        atomicAdd(&hist[v.y], 1.f);
        atomicAdd(&hist[v.z], 1.f);
        atomicAdd(&hist[v.w], 1.f);
    }
    __syncthreads();
    if (tid < NCLS) atomicAdd(&counts[n * NCLS + tid], hist[tid]);

    const int wave = tid >> 6;
    const int lane = tid & 63;

    for (int c = wave; c < NCLS; c += 4) {
        float accS[NCLS], accT[NCLS];
#pragma unroll
        for (int k = 0; k < NCLS; ++k) { accS[k] = 0.f; accT[k] = 0.f; }

        const float4* sp = (const float4*)(S + ((long)(n * NCLS + c)) * HW + pixbase);
        const float4* tp = (const float4*)(T + ((long)(n * NCLS + c)) * HW + pixbase);

        for (int p = lane; p < CHUNK / 4; p += 64) {
            float4 sv = sp[p];
            float4 tv = tp[p];
            int4   lv = ((const int4*)lab)[p];
#pragma unroll
            for (int k = 0; k < NCLS; ++k) {
                float m0 = (lv.x == k) ? 1.f : 0.f;
                float m1 = (lv.y == k) ? 1.f : 0.f;
                float m2 = (lv.z == k) ? 1.f : 0.f;
                float m3 = (lv.w == k) ? 1.f : 0.f;
                accS[k] = fmaf(m0, sv.x, accS[k]);
                accT[k] = fmaf(m0, tv.x, accT[k]);
                accS[k] = fmaf(m1, sv.y, accS[k]);
                accT[k] = fmaf(m1, tv.y, accT[k]);
                accS[k] = fmaf(m2, sv.z, accS[k]);
                accT[k] = fmaf(m2, tv.z, accT[k]);
                accS[k] = fmaf(m3, sv.w, accS[k]);
                accT[k] = fmaf(m3, tv.w, accT[k]);
            }
        }

        // wave-level reduce each accumulator, then one atomic per (c,k)
#pragma unroll
        for (int k = 0; k < NCLS; ++k) {
            float aS = accS[k], aT = accT[k];
            for (int off = 32; off > 0; off >>= 1) {
                aS += __shfl_down(aS, off, 64);
                aT += __shfl_down(aT, off, 64);
            }
            if (lane == 0) {
                atomicAdd(&sums[(( (long)n * 2 + 0) * NCLS + c) * NCLS + k], aS);
                atomicAdd(&sums[(( (long)n * 2 + 1) * NCLS + c) * NCLS + k], aT);
            }
        }
    }
}

__global__ __launch_bounds__(256) void icl_final(
    const float* __restrict__ sums, const float* __restrict__ counts,
    float* __restrict__ out)
{
    __shared__ float v[NB][2][NCLS][NCLS];   // [n][t][k][c]
    __shared__ float red[256];
    const int tid = threadIdx.x;

    // means: sums layout [n][t][c][k] -> v[n][t][k][c]
    for (int i = tid; i < SUMS_ELEMS; i += 256) {
        int k = i % NCLS;
        int c = (i / NCLS) % NCLS;
        int t = (i / (NCLS * NCLS)) % 2;
        int n = i / (2 * NCLS * NCLS);
        float cnt = counts[n * NCLS + k];
        v[n][t][k][c] = sums[i] * (1.f / (cnt + EPSM));
    }
    __syncthreads();

    float acc = 0.f;
    const int NPAIR = NCLS * (NCLS - 1) / 2;   // 171
    for (int i = tid; i < NB * NPAIR; i += 256) {
        int n = i / NPAIR;
        int rem = i % NPAIR;
        int k1 = 0;
        while (rem >= NCLS - 1 - k1) { rem -= NCLS - 1 - k1; ++k1; }
        int k2 = k1 + 1 + rem;
        float ss = 0.f, st = 0.f;
#pragma unroll
        for (int c = 0; c < NCLS; ++c) {
            float ds = v[n][0][k1][c] - v[n][0][k2][c] + EPSPD;
            float dt = v[n][1][k1][c] - v[n][1][k2][c] + EPSPD;
            ss = fmaf(ds, ds, ss);
            st = fmaf(dt, dt, st);
        }
        float e = sqrtf(st) - sqrtf(ss);
        acc += 0.5f * e * e;
    }

    red[tid] = acc;
    __syncthreads();
    for (int s = 128; s > 0; s >>= 1) {
        if (tid < s) red[tid] += red[tid + s];
        __syncthreads();
    }
    if (tid == 0) out[0] = 0.5f * red[0] / (float)NB;
}

extern "C" void kernel_launch(void* const* d_in, const int* in_sizes, int n_in,
                              void* d_out, int out_size, void* d_ws, size_t ws_size,
                              hipStream_t stream) {
    const float* S  = (const float*)d_in[0];
    const float* T  = (const float*)d_in[1];
    const int*   gt = (const int*)d_in[2];

    float* sums   = (float*)d_ws;
    float* counts = sums + SUMS_ELEMS;

    hipMemsetAsync(d_ws, 0, (SUMS_ELEMS + CNT_ELEMS) * sizeof(float), stream);

    dim3 grid(HW / CHUNK, NB);
    icl_sums<<<grid, 256, 0, stream>>>(S, T, gt, sums, counts);
    icl_final<<<1, 256, 0, stream>>>(sums, counts, (float*)d_out);
}

// Round 2
// 222.711 us; speedup vs baseline: 1.4880x; 1.4880x over previous
//
#include <hip/hip_runtime.h>

#define NCLS 19
#define HWSZ (512*1024)
#define NB   8
#define CHUNK 4096            // pixels per block
#define PERW  (CHUNK/4)       // 1024 pixels per wave
#define STEPS (PERW/16)       // 64 K-steps of 16 pixels
#define EPSM  1e-6f
#define EPSPD 1e-6f

// ws: sums[n][t][row 0..19][col 0..31] f32; row=channel (t=0 row19 = counts), col=class
#define ROWP 20
#define COLP 32
#define SUMS_ELEMS (NB*2*ROWP*COLP)

typedef short bf16x8 __attribute__((ext_vector_type(8)));
typedef float f32x16 __attribute__((ext_vector_type(16)));

__device__ __forceinline__ short bfh(float v) {
    return (short)(__builtin_bit_cast(unsigned, v) >> 16);
}
__device__ __forceinline__ short bfl(float v) {
    unsigned u = __builtin_bit_cast(unsigned, v);
    float lf = v - __builtin_bit_cast(float, u & 0xFFFF0000u);
    return (short)(__builtin_bit_cast(unsigned, lf) >> 16);
}

__global__ __launch_bounds__(256, 4) void icl_sums(
    const float* __restrict__ S, const float* __restrict__ T,
    const int* __restrict__ gt, float* __restrict__ sums)
{
    __shared__ int   lab[CHUNK];
    __shared__ float red[2][ROWP][COLP];

    const int tid = threadIdx.x;
    const int n   = blockIdx.y;
    const long chunk0 = (long)blockIdx.x * CHUNK;

    for (int i = tid; i < 2 * ROWP * COLP; i += 256) ((float*)red)[i] = 0.f;

    const int4* gp = (const int4*)(gt + (long)n * HWSZ + chunk0);
    for (int i = tid; i < CHUNK / 4; i += 256) ((int4*)lab)[i] = gp[i];
    __syncthreads();

    const int lane = tid & 63;
    const int wave = tid >> 6;
    const int r    = lane & 31;     // A-row (channel) / B-col (class)
    const int kg   = lane >> 5;     // k-group: 8-pixel half of the 16-pixel step

    f32x16 accS = {0,0,0,0,0,0,0,0,0,0,0,0,0,0,0,0};
    f32x16 accT = {0,0,0,0,0,0,0,0,0,0,0,0,0,0,0,0};

    const int  wbase  = wave * PERW;
    const bool isload = (r < NCLS);
    const bool isone  = (r == NCLS);        // count row: A_hi = 1.0, A_lo = 0
    const float* Sp = S + ((long)(n * NCLS + (isload ? r : 0))) * HWSZ + chunk0;
    const float* Tp = T + ((long)(n * NCLS + (isload ? r : 0))) * HWSZ + chunk0;

    const bf16x8 ones = {0x3F80,0x3F80,0x3F80,0x3F80,0x3F80,0x3F80,0x3F80,0x3F80};
    const bf16x8 zer  = {0,0,0,0,0,0,0,0};

    for (int s = 0; s < STEPS; ++s) {
        const int pb = wbase + s * 16 + kg * 8;

        // B fragment: one-hot of labels (exact in bf16)
        const int4 l0 = *(const int4*)&lab[pb];
        const int4 l1 = *(const int4*)&lab[pb + 4];
        bf16x8 B;
        B[0] = (l0.x == r) ? (short)0x3F80 : (short)0;
        B[1] = (l0.y == r) ? (short)0x3F80 : (short)0;
        B[2] = (l0.z == r) ? (short)0x3F80 : (short)0;
        B[3] = (l0.w == r) ? (short)0x3F80 : (short)0;
        B[4] = (l1.x == r) ? (short)0x3F80 : (short)0;
        B[5] = (l1.y == r) ? (short)0x3F80 : (short)0;
        B[6] = (l1.z == r) ? (short)0x3F80 : (short)0;
        B[7] = (l1.w == r) ? (short)0x3F80 : (short)0;

        bf16x8 sh = zer, sl = zer, th = zer, tl = zer;
        if (isload) {
            const float4 a0 = *(const float4*)(Sp + pb);
            const float4 a1 = *(const float4*)(Sp + pb + 4);
            const float4 b0 = *(const float4*)(Tp + pb);
            const float4 b1 = *(const float4*)(Tp + pb + 4);
            sh[0]=bfh(a0.x); sl[0]=bfl(a0.x);  sh[1]=bfh(a0.y); sl[1]=bfl(a0.y);
            sh[2]=bfh(a0.z); sl[2]=bfl(a0.z);  sh[3]=bfh(a0.w); sl[3]=bfl(a0.w);
            sh[4]=bfh(a1.x); sl[4]=bfl(a1.x);  sh[5]=bfh(a1.y); sl[5]=bfl(a1.y);
            sh[6]=bfh(a1.z); sl[6]=bfl(a1.z);  sh[7]=bfh(a1.w); sl[7]=bfl(a1.w);
            th[0]=bfh(b0.x); tl[0]=bfl(b0.x);  th[1]=bfh(b0.y); tl[1]=bfl(b0.y);
            th[2]=bfh(b0.z); tl[2]=bfl(b0.z);  th[3]=bfh(b0.w); tl[3]=bfl(b0.w);
            th[4]=bfh(b1.x); tl[4]=bfl(b1.x);  th[5]=bfh(b1.y); tl[5]=bfl(b1.y);
            th[6]=bfh(b1.z); tl[6]=bfl(b1.z);  th[7]=bfh(b1.w); tl[7]=bfl(b1.w);
        }
        if (isone) sh = ones;

        accS = __builtin_amdgcn_mfma_f32_32x32x16_bf16(sh, B, accS, 0, 0, 0);
        accS = __builtin_amdgcn_mfma_f32_32x32x16_bf16(sl, B, accS, 0, 0, 0);
        accT = __builtin_amdgcn_mfma_f32_32x32x16_bf16(th, B, accT, 0, 0, 0);
        accT = __builtin_amdgcn_mfma_f32_32x32x16_bf16(tl, B, accT, 0, 0, 0);
    }

    // C/D layout (verified): col = lane&31, row = (reg&3) + 8*(reg>>2) + 4*(lane>>5)
#pragma unroll
    for (int e = 0; e < 16; ++e) {
        const int row = (e & 3) + 8 * (e >> 2) + 4 * kg;
        if (row < ROWP) {
            atomicAdd(&red[0][row][r], accS[e]);
            atomicAdd(&red[1][row][r], accT[e]);
        }
    }
    __syncthreads();

    float* gs = sums + (long)n * 2 * ROWP * COLP;
    for (int i = tid; i < 2 * ROWP * COLP; i += 256) {
        const int col = i & 31;
        if (col < NCLS) {
            const float v = ((const float*)red)[i];
            atomicAdd(&gs[i], v);
        }
    }
}

__global__ __launch_bounds__(256) void icl_final(
    const float* __restrict__ sums, float* __restrict__ out)
{
    __shared__ float v[NB][2][NCLS][NCLS];   // [n][t][k][c]
    __shared__ float red2[256];
    const int tid = threadIdx.x;

    for (int i = tid; i < NB * 2 * NCLS * NCLS; i += 256) {
        const int c = i % NCLS;
        const int k = (i / NCLS) % NCLS;
        const int t = (i / (NCLS * NCLS)) % 2;
        const int n = i / (2 * NCLS * NCLS);
        const float cnt = sums[((n * 2 + 0) * ROWP + NCLS) * COLP + k];
        const float val = sums[((n * 2 + t) * ROWP + c) * COLP + k];
        v[n][t][k][c] = val * (1.f / (cnt + EPSM));
    }
    __syncthreads();

    float acc = 0.f;
    const int NPAIR = NCLS * (NCLS - 1) / 2;   // 171
    for (int i = tid; i < NB * NPAIR; i += 256) {
        const int n = i / NPAIR;
        int rem = i % NPAIR;
        int k1 = 0;
        while (rem >= NCLS - 1 - k1) { rem -= NCLS - 1 - k1; ++k1; }
        const int k2 = k1 + 1 + rem;
        float ss = 0.f, st = 0.f;
#pragma unroll
        for (int c = 0; c < NCLS; ++c) {
            const float ds = v[n][0][k1][c] - v[n][0][k2][c] + EPSPD;
            const float dt = v[n][1][k1][c] - v[n][1][k2][c] + EPSPD;
            ss = fmaf(ds, ds, ss);
            st = fmaf(dt, dt, st);
        }
        const float e = sqrtf(st) - sqrtf(ss);
        acc += 0.5f * e * e;
    }

    red2[tid] = acc;
    __syncthreads();
    for (int s = 128; s > 0; s >>= 1) {
        if (tid < s) red2[tid] += red2[tid + s];
        __syncthreads();
    }
    if (tid == 0) out[0] = 0.5f * red2[0] / (float)NB;
}

extern "C" void kernel_launch(void* const* d_in, const int* in_sizes, int n_in,
                              void* d_out, int out_size, void* d_ws, size_t ws_size,
                              hipStream_t stream) {
    const float* S  = (const float*)d_in[0];
    const float* T  = (const float*)d_in[1];
    const int*   gt = (const int*)d_in[2];

    float* sums = (float*)d_ws;
    hipMemsetAsync(d_ws, 0, SUMS_ELEMS * sizeof(float), stream);

    dim3 grid(HWSZ / CHUNK, NB);   // (128, 8) = 1024 blocks
    icl_sums<<<grid, 256, 0, stream>>>(S, T, gt, sums);
    icl_final<<<1, 256, 0, stream>>>(sums, (float*)d_out);
}